// Round 8
// baseline (97.163 us; speedup 1.0000x reference)
//
#include <hip/hip_runtime.h>

#define IMG 8
#define LH 150
#define LQ 10
#define KITER 10   // 9 scan steps + final conv
#define ROW (IMG * IMG + 2)   // 66 floats per batch row

// DPP lane shifts within 16-lane rows — VALU pipe, zero LDS involvement.
// ROW_SHR1: lane i <- lane i-1;  ROW_SHL1: lane i <- lane i+1.
// All lanes that would receive cross-row/cross-item garbage are exactly the
// x==0 / x==7 lanes, which are zeroed by mskL/mskR afterwards.
#define DPP_ROW_SHR1 0x111
#define DPP_ROW_SHL1 0x101
template <int CTRL>
__device__ __forceinline__ float dppf(float v) {
    return __builtin_bit_cast(float,
        __builtin_amdgcn_update_dpp(0, __builtin_bit_cast(int, v),
                                    CTRL, 0xF, 0xF, true));
}

// ds_bpermute (byte address); epilogue only. Full-wave convergence required.
__device__ __forceinline__ float bperm(int byte_addr, float v) {
    return __builtin_bit_cast(float,
        __builtin_amdgcn_ds_bpermute(byte_addr, __builtin_bit_cast(int, v)));
}

// ---------------------------------------------------------------------------
// Pre-kernel: collapse h/r convs (exact — no nonlinearity between h and r).
//   ws[t] = sum_c Wr[c] * Wh[c, t]  (t=0..8),  ws[9] = sum_c Wr[c] * bh[c]
// ---------------------------------------------------------------------------
__global__ void weff_kernel(const float* __restrict__ Wh,
                            const float* __restrict__ bh,
                            const float* __restrict__ Wr,
                            float* __restrict__ ws) {
    const int wv = threadIdx.x >> 6;   // 0..9 (wave-uniform)
    const int lane = threadIdx.x & 63;
    float partial = 0.f;
    for (int c = lane; c < LH; c += 64) {
        const float wr = Wr[c];
        partial += wr * ((wv < 9) ? Wh[c * 9 + wv] : bh[c]);
    }
    #pragma unroll
    for (int off = 32; off > 0; off >>= 1)
        partial += __shfl_xor(partial, off);   // full wave active
    if (lane == 0) ws[wv] = partial;
}

// ---------------------------------------------------------------------------
// Main kernel, round-8 layout: one wave = EIGHT items; lane = (item i, col x),
// i = lane>>3, x = lane&7; each lane holds the item's full column (8 rows) in
// 8 VGPRs.  dy taps = register offsets (compile-time, exact zero-pad by term
// omission).  dx taps = DPP row shifts (VALU) + x-edge mask.  The k-loop has
// ZERO LDS-pipe ops (round-6/7 were co-bound on the per-CU LDS pipe from 18
// bpermutes/iter).  Weights stay wave-uniform SGPR reads — per-lane weight
// arrays are an AGPR-spill trap (round 7: VGPR_Count=72 + accvgpr churn).
// ---------------------------------------------------------------------------
__global__ __launch_bounds__(256, 2) void vin_kernel(
    const float* __restrict__ S,
    const float* __restrict__ Wq,
    const float* __restrict__ w,
    const float* __restrict__ Wfc,
    const float* __restrict__ ws,
    float* __restrict__ out,
    int B) {
    const int wave = threadIdx.x >> 6;
    const int lane = threadIdx.x & 63;
    const long wid = (long)blockIdx.x * 4 + wave;   // 8 items per wave
    if (wid * 8 >= B) return;                        // wave-uniform

    const int x = lane & 7;
    const int irow = (lane >> 3) * ROW;
    const float mskL = (x == 0) ? 0.f : 1.f;
    const float mskR = (x == 7) ? 0.f : 1.f;

    const float* Sw = S + wid * 8 * ROW;

    // Column load: X[y] = grid(y, x) of item i.
    float X[8];
    #pragma unroll
    for (int y = 0; y < 8; ++y) X[y] = Sw[irow + y * 8 + x];
    const int s1 = (int)Sw[irow + 64];
    const int s2 = (int)Sw[irow + 65];
    const int selb = ((lane & 56) + s2) << 2;   // lane of (item i, x=s2), bytes

    // ---- r = conv(X, Weff, pad=1) + beff ----
    float XL[8], XR[8];
    #pragma unroll
    for (int y = 0; y < 8; ++y) {
        XL[y] = dppf<DPP_ROW_SHR1>(X[y]) * mskL;
        XR[y] = dppf<DPP_ROW_SHL1>(X[y]) * mskR;
    }
    float r[8];
    #pragma unroll
    for (int y = 0; y < 8; ++y) {
        float acc = ws[9];
        #pragma unroll
        for (int t = 0; t < 9; ++t) {
            const int dy = t / 3 - 1, dx = t % 3 - 1;
            const int yy = y + dy;
            if (yy < 0 || yy > 7) continue;          // exact zero-pad
            const float val = (dx < 0) ? XL[yy] : ((dx > 0) ? XR[yy] : X[yy]);
            acc = fmaf(ws[t], val, acc);
        }
        r[y] = acc;
    }

    // ---- qr[o][y] = conv(r, Wq, pad=1) — loop-invariant across iterations ----
    float rL[8], rR[8];
    #pragma unroll
    for (int y = 0; y < 8; ++y) {
        rL[y] = dppf<DPP_ROW_SHR1>(r[y]) * mskL;
        rR[y] = dppf<DPP_ROW_SHL1>(r[y]) * mskR;
    }
    float qr[LQ][8];
    #pragma unroll
    for (int o = 0; o < LQ; ++o) {
        #pragma unroll
        for (int y = 0; y < 8; ++y) {
            float acc = 0.f;
            #pragma unroll
            for (int t = 0; t < 9; ++t) {
                const int dy = t / 3 - 1, dx = t % 3 - 1;
                const int yy = y + dy;
                if (yy < 0 || yy > 7) continue;
                const float val = (dx < 0) ? rL[yy] : ((dx > 0) ? rR[yy] : r[yy]);
                acc = fmaf(val, Wq[o * 9 + t], acc);
            }
            qr[o][y] = acc;
        }
    }

    // v0[y] = max_o qr[o][y]
    float v[8];
    #pragma unroll
    for (int y = 0; y < 8; ++y) {
        float m = qr[0][y];
        #pragma unroll
        for (int o = 1; o < LQ; ++o) m = fmaxf(m, qr[o][y]);
        v[y] = m;
    }

    // ---- 9 scan steps: DPP shifts + fma + running max. NO LDS ops. ----
    #pragma unroll 1   // keep body in I-cache (~800 inst); inner loops unrolled
    for (int k = 0; k < KITER - 1; ++k) {
        float vL[8], vR[8];
        #pragma unroll
        for (int y = 0; y < 8; ++y) {
            vL[y] = dppf<DPP_ROW_SHR1>(v[y]) * mskL;
            vR[y] = dppf<DPP_ROW_SHL1>(v[y]) * mskR;
        }
        float m[8];
        #pragma unroll
        for (int o = 0; o < LQ; ++o) {
            #pragma unroll
            for (int y = 0; y < 8; ++y) {
                float acc = qr[o][y];
                #pragma unroll
                for (int t = 0; t < 9; ++t) {
                    const int dy = t / 3 - 1, dx = t % 3 - 1;
                    const int yy = y + dy;
                    if (yy < 0 || yy > 7) continue;
                    const float val = (dx < 0) ? vL[yy] : ((dx > 0) ? vR[yy] : v[yy]);
                    acc = fmaf(val, w[o * 9 + t], acc);   // w: wave-uniform SGPR
                }
                m[y] = (o == 0) ? acc : fmaxf(m[y], acc);
            }
        }
        #pragma unroll
        for (int y = 0; y < 8; ++y) v[y] = m[y];
    }

    // ---- Final conv fused with pixel-select + FC ----
    // Per-lane FC row: lane x emits logit a=x of its item.
    float wfc[LQ];
    #pragma unroll
    for (int o = 0; o < LQ; ++o) wfc[o] = Wfc[x * LQ + o];

    float vL[8], vR[8];
    #pragma unroll
    for (int y = 0; y < 8; ++y) {
        vL[y] = dppf<DPP_ROW_SHR1>(v[y]) * mskL;
        vR[y] = dppf<DPP_ROW_SHL1>(v[y]) * mskR;
    }
    const bool sb0 = (s1 & 1) != 0, sb1 = (s1 & 2) != 0, sb2 = (s1 & 4) != 0;
    float logit = 0.f;
    #pragma unroll
    for (int o = 0; o < LQ; ++o) {
        float q[8];
        #pragma unroll
        for (int y = 0; y < 8; ++y) {
            float acc = qr[o][y];
            #pragma unroll
            for (int t = 0; t < 9; ++t) {
                const int dy = t / 3 - 1, dx = t % 3 - 1;
                const int yy = y + dy;
                if (yy < 0 || yy > 7) continue;
                const float val = (dx < 0) ? vL[yy] : ((dx > 0) ? vR[yy] : v[yy]);
                acc = fmaf(val, w[o * 9 + t], acc);
            }
            q[y] = acc;
        }
        // y-select (s1) via 3-level cndmask tree, then x-select (s2) via bperm.
        const float a0 = sb0 ? q[1] : q[0];
        const float a1 = sb0 ? q[3] : q[2];
        const float a2 = sb0 ? q[5] : q[4];
        const float a3 = sb0 ? q[7] : q[6];
        const float c0 = sb1 ? a1 : a0;
        const float c1 = sb1 ? a3 : a2;
        const float qy = sb2 ? c1 : c0;
        const float qsel = bperm(selb, qy);       // full convergence
        logit = fmaf(qsel, wfc[o], logit);
    }

    // 64 lanes = 8 items x 8 logits, fully coalesced.
    out[wid * 64 + lane] = logit;
}

extern "C" void kernel_launch(void* const* d_in, const int* in_sizes, int n_in,
                              void* d_out, int out_size, void* d_ws, size_t ws_size,
                              hipStream_t stream) {
    const float* S   = (const float*)d_in[0];
    const float* Wh  = (const float*)d_in[1];
    const float* bh  = (const float*)d_in[2];
    const float* Wr  = (const float*)d_in[3];
    const float* Wq  = (const float*)d_in[4];
    const float* w   = (const float*)d_in[5];
    const float* Wfc = (const float*)d_in[6];
    float* out = (float*)d_out;
    float* ws  = (float*)d_ws;

    const int B = in_sizes[0] / ROW;

    weff_kernel<<<1, 640, 0, stream>>>(Wh, bh, Wr, ws);

    // 4 waves/block, 8 items/wave => 32 items per block.
    const int grid = (B + 31) / 32;
    vin_kernel<<<grid, 256, 0, stream>>>(S, Wq, w, Wfc, ws, out, B);
}